// Round 10
// baseline (366.124 us; speedup 1.0000x reference)
//
#include <hip/hip_runtime.h>
#include <hip/hip_bf16.h>
#include <math.h>

#define DM   512
#define DI   1024
#define NS   64
#define RDT  32
#define BB   2
#define LL   1000
#define MROWS (BB*LL)   // 2000

typedef __attribute__((ext_vector_type(8))) short bf16x8;
typedef __attribute__((ext_vector_type(4))) float f32x4;

// f32 -> bf16 RNE (finite inputs)
__device__ __forceinline__ unsigned short f2bf(float f) {
    unsigned u = __builtin_bit_cast(unsigned, f);
    u = (u + 0x7FFF + ((u >> 16) & 1)) >> 16;
    return (unsigned short)u;
}
__device__ __forceinline__ float bf2f(unsigned short h) {
    unsigned u = (unsigned)h << 16;
    return __builtin_bit_cast(float, u);
}
__device__ __forceinline__ float bcast_lane(float v, int lane) {
    return __builtin_bit_cast(float,
        __builtin_amdgcn_readlane(__builtin_bit_cast(int, v), lane));
}

// ------------------- rmsnorm -> per-dir bf16 (norm_w folded) ----------------
__global__ __launch_bounds__(256)
void rmsnorm_k(const float* __restrict__ x,
               const float* __restrict__ nw0, const float* __restrict__ nw1,
               unsigned short* __restrict__ xnb0, unsigned short* __restrict__ xnb1) {
    int row = blockIdx.x;
    int tid = threadIdx.x;
    const float* xr = x + (size_t)row * DM;
    float2 v = *(const float2*)(xr + tid * 2);
    float ss = v.x * v.x + v.y * v.y;
    #pragma unroll
    for (int off = 32; off; off >>= 1) ss += __shfl_xor(ss, off, 64);
    __shared__ float red[4];
    if ((tid & 63) == 0) red[tid >> 6] = ss;
    __syncthreads();
    float tot = red[0] + red[1] + red[2] + red[3];
    float scale = rsqrtf(tot / (float)DM + 1e-5f);
    float2 w0 = *(const float2*)(nw0 + tid * 2);
    float2 w1 = *(const float2*)(nw1 + tid * 2);
    short2 o0, o1;
    o0.x = (short)f2bf(v.x * scale * w0.x);
    o0.y = (short)f2bf(v.y * scale * w0.y);
    o1.x = (short)f2bf(v.x * scale * w1.x);
    o1.y = (short)f2bf(v.y * scale * w1.y);
    *(short2*)(xnb0 + (size_t)row * DM + tid * 2) = o0;
    *(short2*)(xnb1 + (size_t)row * DM + tid * 2) = o1;
}

// ------------------------------------ f32 -> bf16 convert, 2 arrays batched --
__global__ __launch_bounds__(256)
void cvt2_k(const float* __restrict__ in0, const float* __restrict__ in1,
            unsigned short* __restrict__ out0, unsigned short* __restrict__ out1,
            int n4) {
    int idx = blockIdx.x * 256 + threadIdx.x;
    if (idx >= n4) return;
    const float* in = blockIdx.y ? in1 : in0;
    unsigned short* out = blockIdx.y ? out1 : out0;
    float4 v = *(const float4*)(in + (size_t)idx * 4);
    short4 o;
    o.x = (short)f2bf(v.x); o.y = (short)f2bf(v.y);
    o.z = (short)f2bf(v.z); o.w = (short)f2bf(v.w);
    *(short4*)(out + (size_t)idx * 4) = o;
}

// ------------- x_proj weights + dt weights -> bf16, one dispatch ------------
__global__ __launch_bounds__(256)
void cvt_xpdw_k(const float* __restrict__ xp0, const float* __restrict__ xp1,
                const float* __restrict__ dw0, const float* __restrict__ dw1,
                unsigned short* __restrict__ oxp0, unsigned short* __restrict__ oxp1,
                unsigned short* __restrict__ odw0, unsigned short* __restrict__ odw1)
{
    int y = blockIdx.y;
    const float* in; unsigned short* out; int n4;
    if (y == 0)      { in = xp0; out = oxp0; n4 = 40960; }
    else if (y == 1) { in = xp1; out = oxp1; n4 = 40960; }
    else if (y == 2) { in = dw0; out = odw0; n4 = 8192; }
    else             { in = dw1; out = odw1; n4 = 8192; }
    int idx = blockIdx.x * 256 + threadIdx.x;
    if (idx >= n4) return;
    float4 v = *(const float4*)(in + (size_t)idx * 4);
    short4 o;
    o.x = (short)f2bf(v.x); o.y = (short)f2bf(v.y);
    o.z = (short)f2bf(v.z); o.w = (short)f2bf(v.w);
    *(short4*)(out + (size_t)idx * 4) = o;
}

// ------ GEMM1 (in_proj) bf16 MFMA: xzb[dir] = bf16( xn_dir @ W^T ) ----------
__global__ __launch_bounds__(256, 2)
void gemm1_mfma(const unsigned short* __restrict__ xnb0,
                const unsigned short* __restrict__ xnb1,
                const unsigned short* __restrict__ wib0,
                const unsigned short* __restrict__ wib1,
                unsigned short* __restrict__ xzb0, unsigned short* __restrict__ xzb1)
{
    __shared__ __align__(16) unsigned short As[128 * 40];
    __shared__ __align__(16) unsigned short Bs[128 * 40];
    int dir = blockIdx.z;
    const unsigned short* A = dir ? xnb1 : xnb0;
    const unsigned short* W = dir ? wib1 : wib0;
    unsigned short* C = dir ? xzb1 : xzb0;
    int n0 = blockIdx.x * 128, m0 = blockIdx.y * 128;
    int tid = threadIdx.x;
    int wv = tid >> 6, lane = tid & 63;
    int wr = wv >> 1, wc = wv & 1;
    int fl = lane & 15, kg = lane >> 4;

    f32x4 acc[4][4];
    #pragma unroll
    for (int i = 0; i < 4; i++)
        #pragma unroll
        for (int j = 0; j < 4; j++) acc[i][j] = (f32x4){0.f, 0.f, 0.f, 0.f};

    int sr = tid >> 2, cg = tid & 3;
    for (int k0 = 0; k0 < 512; k0 += 32) {
        #pragma unroll
        for (int i = 0; i < 2; i++) {
            int row = sr + i * 64;
            int m = m0 + row;
            float4 av = make_float4(0.f, 0.f, 0.f, 0.f);
            if (m < MROWS) {
                int rs = m;
                if (dir) { int b = m / LL, t = m % LL; rs = b * LL + (LL - 1 - t); }
                av = *(const float4*)(A + (size_t)rs * 512 + k0 + cg * 8);
            }
            *(float4*)(&As[row * 40 + cg * 8]) = av;
            float4 wv4 = *(const float4*)(W + (size_t)(n0 + row) * 512 + k0 + cg * 8);
            *(float4*)(&Bs[row * 40 + cg * 8]) = wv4;
        }
        __syncthreads();
        bf16x8 af[4], bf[4];
        #pragma unroll
        for (int fr = 0; fr < 4; fr++)
            af[fr] = *(const bf16x8*)(&As[(wr * 64 + fr * 16 + fl) * 40 + kg * 8]);
        #pragma unroll
        for (int fc = 0; fc < 4; fc++)
            bf[fc] = *(const bf16x8*)(&Bs[(wc * 64 + fc * 16 + fl) * 40 + kg * 8]);
        #pragma unroll
        for (int fr = 0; fr < 4; fr++)
            #pragma unroll
            for (int fc = 0; fc < 4; fc++)
                acc[fr][fc] = __builtin_amdgcn_mfma_f32_16x16x32_bf16(
                    af[fr], bf[fc], acc[fr][fc], 0, 0, 0);
        __syncthreads();
    }
    #pragma unroll
    for (int fr = 0; fr < 4; fr++)
        #pragma unroll
        for (int fc = 0; fc < 4; fc++)
            #pragma unroll
            for (int j = 0; j < 4; j++) {
                int m = m0 + wr * 64 + fr * 16 + kg * 4 + j;
                if (m < MROWS) {
                    int n = n0 + wc * 64 + fc * 16 + fl;
                    C[(size_t)m * 2048 + n] = f2bf(acc[fr][fc][j]);
                }
            }
}

// -------- out_proj bf16 MFMA, 128x128 tile, full K, per-dir -> partials -----
__global__ __launch_bounds__(256, 2)
void gemm_out_mfma(const unsigned short* __restrict__ ygb0,
                   const unsigned short* __restrict__ ygb1,
                   const unsigned short* __restrict__ wob0,
                   const unsigned short* __restrict__ wob1,
                   float* __restrict__ partial)
{
    __shared__ __align__(16) unsigned short As[128 * 40];
    __shared__ __align__(16) unsigned short Bs[128 * 40];
    int dir = blockIdx.z;
    const unsigned short* A = dir ? ygb1 : ygb0;   // (2000,1024)
    const unsigned short* W = dir ? wob1 : wob0;   // (512,1024)
    float* P = partial + (size_t)dir * MROWS * 512;
    int n0 = blockIdx.x * 128, m0 = blockIdx.y * 128;
    int tid = threadIdx.x;
    int wv = tid >> 6, lane = tid & 63;
    int wr = wv >> 1, wc = wv & 1;
    int fl = lane & 15, kg = lane >> 4;

    f32x4 acc[4][4];
    #pragma unroll
    for (int i = 0; i < 4; i++)
        #pragma unroll
        for (int j = 0; j < 4; j++) acc[i][j] = (f32x4){0.f, 0.f, 0.f, 0.f};

    int sr = tid >> 2, cg = tid & 3;
    for (int k0 = 0; k0 < 1024; k0 += 32) {
        #pragma unroll
        for (int i = 0; i < 2; i++) {
            int row = sr + i * 64;
            int m = m0 + row;
            float4 av = make_float4(0.f, 0.f, 0.f, 0.f);
            if (m < MROWS)
                av = *(const float4*)(A + (size_t)m * 1024 + k0 + cg * 8);
            *(float4*)(&As[row * 40 + cg * 8]) = av;
            float4 wv4 = *(const float4*)(W + (size_t)(n0 + row) * 1024 + k0 + cg * 8);
            *(float4*)(&Bs[row * 40 + cg * 8]) = wv4;
        }
        __syncthreads();
        bf16x8 af[4], bf[4];
        #pragma unroll
        for (int fr = 0; fr < 4; fr++)
            af[fr] = *(const bf16x8*)(&As[(wr * 64 + fr * 16 + fl) * 40 + kg * 8]);
        #pragma unroll
        for (int fc = 0; fc < 4; fc++)
            bf[fc] = *(const bf16x8*)(&Bs[(wc * 64 + fc * 16 + fl) * 40 + kg * 8]);
        #pragma unroll
        for (int fr = 0; fr < 4; fr++)
            #pragma unroll
            for (int fc = 0; fc < 4; fc++)
                acc[fr][fc] = __builtin_amdgcn_mfma_f32_16x16x32_bf16(
                    af[fr], bf[fc], acc[fr][fc], 0, 0, 0);
        __syncthreads();
    }
    #pragma unroll
    for (int fr = 0; fr < 4; fr++)
        #pragma unroll
        for (int fc = 0; fc < 4; fc++)
            #pragma unroll
            for (int j = 0; j < 4; j++) {
                int m = m0 + wr * 64 + fr * 16 + kg * 4 + j;
                if (m < MROWS) {
                    int n = n0 + wc * 64 + fc * 16 + fl;
                    P[(size_t)m * 512 + n] = acc[fr][fc][j];
                }
            }
}

// out[m] = 2x[m] + pf[m] + pb[flip(m)]
__global__ __launch_bounds__(256)
void reduce_out_k(const float* __restrict__ x, const float* __restrict__ partial,
                  float* __restrict__ out)
{
    int idx = blockIdx.x * 256 + threadIdx.x;
    if (idx >= MROWS * 128) return;
    int m = idx >> 7, q = idx & 127;
    int b = m / LL, t = m % LL;
    int fm = b * LL + (LL - 1 - t);
    const float* p0 = partial;
    const float* p1 = partial + (size_t)MROWS * 512;
    float4 xv = *(const float4*)(x  + (size_t)m  * 512 + q * 4);
    float4 a  = *(const float4*)(p0 + (size_t)m  * 512 + q * 4);
    float4 c  = *(const float4*)(p1 + (size_t)fm * 512 + q * 4);
    float4 o;
    o.x = 2.f * xv.x + a.x + c.x;
    o.y = 2.f * xv.y + a.y + c.y;
    o.z = 2.f * xv.z + a.z + c.z;
    o.w = 2.f * xv.w + a.w + c.w;
    *(float4*)(out + (size_t)m * 512 + q * 4) = o;
}

// ---- causal dwconv + silu -> ucb bf16 [b][d][t]  AND  xcb bf16 [t][d] ------
__global__ __launch_bounds__(256)
void conv_silu_k(const unsigned short* __restrict__ xzb0,
                 const unsigned short* __restrict__ xzb1,
                 const float* __restrict__ cw0, const float* __restrict__ cw1,
                 const float* __restrict__ cb0, const float* __restrict__ cb1,
                 unsigned short* __restrict__ ucb0, unsigned short* __restrict__ ucb1,
                 unsigned short* __restrict__ xcb0, unsigned short* __restrict__ xcb1)
{
    __shared__ float Ls[64 * 65];
    int dirb = blockIdx.z;
    int dir = dirb >> 1, b = dirb & 1;
    int d0 = blockIdx.x * 64, t0 = blockIdx.y * 64;
    int tid = threadIdx.x;
    int dl = tid & 63, tg = tid >> 6;

    const unsigned short* in = (dir ? xzb1 : xzb0) + (size_t)b * LL * 2048;
    const float* cw = dir ? cw1 : cw0;
    const float* cb = dir ? cb1 : cb0;
    unsigned short* ucb = dir ? ucb1 : ucb0;
    unsigned short* xcb = dir ? xcb1 : xcb0;

    float4 w4 = ((const float4*)cw)[d0 + dl];
    float bias = cb[d0 + dl];

    int ts = t0 + tg * 16;
    float x3 = 0.f, x2 = 0.f, x1 = 0.f;
    if (ts - 3 >= 0 && ts - 3 < LL) x3 = bf2f(in[(size_t)(ts - 3) * 2048 + d0 + dl]);
    if (ts - 2 >= 0 && ts - 2 < LL) x2 = bf2f(in[(size_t)(ts - 2) * 2048 + d0 + dl]);
    if (ts - 1 >= 0 && ts - 1 < LL) x1 = bf2f(in[(size_t)(ts - 1) * 2048 + d0 + dl]);

    #pragma unroll
    for (int i = 0; i < 16; i++) {
        int t = ts + i;
        float x0v = (t < LL) ? bf2f(in[(size_t)t * 2048 + d0 + dl]) : 0.f;
        float a = bias + x3 * w4.x + x2 * w4.y + x1 * w4.z + x0v * w4.w;
        float s = a / (1.f + __expf(-a));
        Ls[dl * 65 + tg * 16 + i] = s;
        if (t < LL)
            xcb[((size_t)(b * LL + t)) * 1024 + d0 + dl] = f2bf(s);
        x3 = x2; x2 = x1; x1 = x0v;
    }
    __syncthreads();
    int tl = tid & 63, dg = tid >> 6;
    #pragma unroll
    for (int i = 0; i < 16; i++) {
        int dd = dg * 16 + i;
        int t = t0 + tl;
        if (t < LL)
            ucb[((size_t)(b * 1024) + d0 + dd) * LL + t] = f2bf(Ls[dd * 65 + tl]);
    }
}

// ---- x_proj bf16 MFMA fused with dt-GEMM + softplus ------------------------
// per (dirb, 64-t tile): x_dbl = xcb @ xp^T;  cols 32..159 -> bct[n-32][t];
// cols 0..31 (dt_raw) -> bf16 -> MFMA with dt_w^T -> softplus -> dtT[d][t]
__global__ __launch_bounds__(256, 2)
void gemm_xp_mfma(const unsigned short* __restrict__ xcb0,
                  const unsigned short* __restrict__ xcb1,
                  const unsigned short* __restrict__ xpb0,
                  const unsigned short* __restrict__ xpb1,
                  const unsigned short* __restrict__ dwb0,
                  const unsigned short* __restrict__ dwb1,
                  const float* __restrict__ db0, const float* __restrict__ db1,
                  float* __restrict__ dtT0, float* __restrict__ dtT1,
                  float* __restrict__ bct)
{
    __shared__ __align__(16) unsigned short As[64 * 40];
    __shared__ __align__(16) unsigned short Ws[160 * 40];
    __shared__ __align__(16) unsigned short Ds[64 * 40];
    int dirb = blockIdx.y;
    int dir = dirb >> 1, b = dirb & 1;
    const unsigned short* A  = (dir ? xcb1 : xcb0) + (size_t)b * LL * 1024;
    const unsigned short* W  = dir ? xpb1 : xpb0;   // (160,1024)
    const unsigned short* DW = dir ? dwb1 : dwb0;   // (1024,32)
    const float* DB = dir ? db1 : db0;
    float* dtT = (dir ? dtT1 : dtT0) + (size_t)b * 1024 * LL;
    float* bc  = bct + (size_t)dirb * 128 * LL;
    int m0 = blockIdx.x * 64;
    int tid = threadIdx.x;
    int wv = tid >> 6, lane = tid & 63;
    int fl = lane & 15, kg = lane >> 4;

    f32x4 acc[10];
    #pragma unroll
    for (int f = 0; f < 10; f++) acc[f] = (f32x4){0.f, 0.f, 0.f, 0.f};

    int sr = tid >> 2, cg = tid & 3;
    for (int k0 = 0; k0 < 1024; k0 += 32) {
        {   // A tile 64x32
            int t = m0 + sr;
            float4 av = make_float4(0.f, 0.f, 0.f, 0.f);
            if (t < LL)
                av = *(const float4*)(A + (size_t)t * 1024 + k0 + cg * 8);
            *(float4*)(&As[sr * 40 + cg * 8]) = av;
        }
        #pragma unroll
        for (int it = 0; it < 3; it++) {   // W tile 160x32
            int row = sr + it * 64;
            if (row < 160) {
                float4 wv4 = *(const float4*)(W + (size_t)row * 1024 + k0 + cg * 8);
                *(float4*)(&Ws[row * 40 + cg * 8]) = wv4;
            }
        }
        __syncthreads();
        bf16x8 af = *(const bf16x8*)(&As[(wv * 16 + fl) * 40 + kg * 8]);
        #pragma unroll
        for (int f = 0; f < 10; f++) {
            bf16x8 bf = *(const bf16x8*)(&Ws[(f * 16 + fl) * 40 + kg * 8]);
            acc[f] = __builtin_amdgcn_mfma_f32_16x16x32_bf16(af, bf, acc[f], 0, 0, 0);
        }
        __syncthreads();
    }

    // ---- B/C columns (n=32..159) -> bct transposed
    #pragma unroll
    for (int f = 2; f < 10; f++) {
        int n = f * 16 + fl;
        #pragma unroll
        for (int j = 0; j < 4; j++) {
            int t = m0 + wv * 16 + kg * 4 + j;
            if (t < LL) bc[(size_t)(n - 32) * LL + t] = acc[f][j];
        }
    }

    // ---- dt_raw (n=0..31) -> bf16 LDS [t_local][32]
    #pragma unroll
    for (int f = 0; f < 2; f++)
        #pragma unroll
        for (int j = 0; j < 4; j++)
            Ds[(wv * 16 + kg * 4 + j) * 40 + f * 16 + fl] = f2bf(acc[f][j]);
    __syncthreads();

    // ---- dt GEMM (K=32, one MFMA per 16-n block) + softplus -> dtT[d][t]
    bf16x8 af2 = *(const bf16x8*)(&Ds[(wv * 16 + fl) * 40 + kg * 8]);
    for (int nb = 0; nb < 64; nb++) {
        bf16x8 bfr = *(const bf16x8*)(DW + (size_t)(nb * 16 + fl) * 32 + kg * 8);
        f32x4 ad = __builtin_amdgcn_mfma_f32_16x16x32_bf16(
            af2, bfr, (f32x4){0.f, 0.f, 0.f, 0.f}, 0, 0, 0);
        float bias = DB[nb * 16 + fl];
        float4 st;
        #pragma unroll
        for (int j = 0; j < 4; j++) {
            float v = ad[j] + bias;
            st[j] = (v > 20.f) ? v : log1pf(__expf(v));
        }
        int tb = m0 + wv * 16 + kg * 4;
        float* drow = dtT + (size_t)(nb * 16 + fl) * LL + tb;
        if (tb + 3 < LL) {
            *(float4*)drow = st;
        } else {
            #pragma unroll
            for (int j = 0; j < 4; j++)
                if (tb + j < LL) drow[j] = st[j];
        }
    }
}

// ------------------------------------------------------------ selective scan
// (unchanged structure; u input now bf16)
__global__ __launch_bounds__(256)
void scan_k(float* __restrict__ dtT0, float* __restrict__ dtT1,
            const unsigned short* __restrict__ ucT0,
            const unsigned short* __restrict__ ucT1,
            const float* __restrict__ bct,
            const float* __restrict__ Al0, const float* __restrict__ Al1,
            const float* __restrict__ Dc0, const float* __restrict__ Dc1)
{
    __shared__ float Bs[64 * 34];
    __shared__ float Cs[64 * 34];
    __shared__ float Pt[4][16 * 66];
    int dirb = blockIdx.y;
    int dir = dirb >> 1, b = dirb & 1;
    int wid = threadIdx.x >> 6, lane = threadIdx.x & 63;
    int d = blockIdx.x * 4 + wid;
    float* Pw = Pt[wid];

    float*       dtT = (dir ? dtT1 : dtT0);
    const unsigned short* ucT = (dir ? ucT1 : ucT0);
    const float* Al  = dir ? Al1 : Al0;
    const float* Dc  = dir ? Dc1 : Dc0;

    float a  = -__expf(Al[d * 64 + lane]) * 1.44269504f;
    float Dp = Dc[d];
    float h  = 0.f;
    size_t chan = ((size_t)(b * 1024 + d)) * LL;
    const float* Bg = bct + (size_t)dirb * 128 * LL;

    int srow = threadIdx.x >> 2;
    int scol = (threadIdx.x & 3) * 8;
    int tl16 = lane & 15, qq = lane >> 4;
    const float* Prow = Pw + tl16 * 66 + qq * 16;

    float4 rb0, rb1, rc0, rc1;
    float dta = 0.f, ua = 0.f;
    {
        const float* Bp = Bg + (size_t)srow * LL + scol;
        const float* Cp = Bg + (size_t)(srow + 64) * LL + scol;
        rb0 = *(const float4*)(Bp);     rb1 = *(const float4*)(Bp + 4);
        rc0 = *(const float4*)(Cp);     rc1 = *(const float4*)(Cp + 4);
        if (lane < 32) {
            dta = dtT[chan + lane];
            ua  = bf2f(ucT[chan + lane]);
        }
    }

    for (int t0 = 0; t0 < LL; t0 += 32) {
        int rem = min(32, LL - t0);
        __syncthreads();
        *(float4*)(&Bs[srow * 34 + scol])     = rb0;
        *(float4*)(&Bs[srow * 34 + scol + 4]) = rb1;
        *(float4*)(&Cs[srow * 34 + scol])     = rc0;
        *(float4*)(&Cs[srow * 34 + scol + 4]) = rc1;
        float dcur = dta, ucur = ua;
        float wsc  = dcur * ucur;
        __syncthreads();

        if (t0 + 32 < LL) {
            const float* Bp = Bg + (size_t)srow * LL + (t0 + 32) + scol;
            const float* Cp = Bg + (size_t)(srow + 64) * LL + (t0 + 32) + scol;
            rb0 = *(const float4*)(Bp);     rb1 = *(const float4*)(Bp + 4);
            rc0 = *(const float4*)(Cp);     rc1 = *(const float4*)(Cp + 4);
            if (lane < min(32, LL - t0 - 32)) {
                dta = dtT[chan + t0 + 32 + lane];
                ua  = bf2f(ucT[chan + t0 + 32 + lane]);
            }
        }

        for (int sec = 0; sec < 2; sec++) {
            int sbase = sec * 16;
            int steps = rem - sbase;
            if (steps <= 0) break;
            if (steps > 16) steps = 16;
            if (steps < 16) {
                for (int i = steps; i < 16; i++) Pw[i * 66 + lane] = 0.f;
            }
            int ngr = (steps + 7) >> 3;
            for (int g = 0; g < ngr; g++) {
                int tb = sbase + g * 8;
                float4 B0 = *(const float4*)(&Bs[lane * 34 + tb]);
                float4 B1 = *(const float4*)(&Bs[lane * 34 + tb + 4]);
                float4 C0 = *(const float4*)(&Cs[lane * 34 + tb]);
                float4 C1 = *(const float4*)(&Cs[lane * 34 + tb + 4]);
                #pragma unroll
                for (int i = 0; i < 8; i++) {
                    float dtv = bcast_lane(dcur, tb + i);
                    float w   = bcast_lane(wsc,  tb + i);
                    float dA  = exp2f(dtv * a);
                    float Bn  = (i < 4) ? B0[i] : B1[i - 4];
                    float Cn  = (i < 4) ? C0[i] : C1[i - 4];
                    h = fmaf(dA, h, w * Bn);
                    Pw[(g * 8 + i) * 66 + lane] = h * Cn;
                }
            }
            float s = 0.f;
            #pragma unroll
            for (int j = 0; j < 8; j++) {
                float2 v = *(const float2*)(Prow + j * 2);
                s += v.x + v.y;
            }
#if __has_builtin(__builtin_amdgcn_permlane32_swap)
            {
                unsigned aa = __builtin_bit_cast(unsigned, s);
                auto r = __builtin_amdgcn_permlane32_swap(aa, aa, false, false);
                s = __builtin_bit_cast(float, (unsigned)r[0]) +
                    __builtin_bit_cast(float, (unsigned)r[1]);
            }
#else
            s += __shfl_xor(s, 32, 64);
#endif
#if __has_builtin(__builtin_amdgcn_permlane16_swap)
            {
                unsigned aa = __builtin_bit_cast(unsigned, s);
                auto r = __builtin_amdgcn_permlane16_swap(aa, aa, false, false);
                s = __builtin_bit_cast(float, (unsigned)r[0]) +
                    __builtin_bit_cast(float, (unsigned)r[1]);
            }
#else
            s += __shfl_xor(s, 16, 64);
#endif
            float uf = __shfl(ucur, sbase + tl16, 64);
            s = fmaf(uf, Dp, s);
            if (lane < steps)
                dtT[chan + t0 + sbase + lane] = s;
        }
    }
}

// ------- gate: ygb[t][d] = bf16( yT[d][t] * silu(z[t][1024+d]) ) ------------
__global__ __launch_bounds__(256)
void gate_k(const float* __restrict__ yT0, const float* __restrict__ yT1,
            const unsigned short* __restrict__ xzb0,
            const unsigned short* __restrict__ xzb1,
            unsigned short* __restrict__ yg0, unsigned short* __restrict__ yg1)
{
    __shared__ float Ls[64 * 65];
    int dirb = blockIdx.z;
    int dir = dirb >> 1, b = dirb & 1;
    int d0 = blockIdx.x * 64, t0 = blockIdx.y * 64;
    int tid = threadIdx.x;
    const float* yT = (dir ? yT1 : yT0) + (size_t)b * 1024 * LL;
    const unsigned short* xz = (dir ? xzb1 : xzb0) + (size_t)b * LL * 2048;
    unsigned short* yg = dir ? yg1 : yg0;

    int tl = tid & 63, dg = tid >> 6;
    #pragma unroll
    for (int i = 0; i < 16; i++) {
        int dd = dg * 16 + i;
        int t = t0 + tl;
        float v = (t < LL) ? yT[(size_t)(d0 + dd) * LL + t] : 0.f;
        Ls[dd * 65 + tl] = v;
    }
    __syncthreads();
    int dcol = tid & 63, tg = tid >> 6;
    #pragma unroll
    for (int i = 0; i < 16; i++) {
        int t = t0 + tg * 16 + i;
        if (t >= LL) continue;
        float z = bf2f(xz[(size_t)t * 2048 + 1024 + d0 + dcol]);
        float y = Ls[dcol * 65 + tg * 16 + i];
        float s = z / (1.f + __expf(-z));
        yg[((size_t)(b * LL + t)) * 1024 + d0 + dcol] = f2bf(y * s);
    }
}

// -------------------------------------------------------------------- launch
extern "C" void kernel_launch(void* const* d_in, const int* in_sizes, int n_in,
                              void* d_out, int out_size, void* d_ws, size_t ws_size,
                              hipStream_t stream) {
    const float* x = (const float*)d_in[0];
    const float* P[2][10];
    for (int dir = 0; dir < 2; dir++)
        for (int i = 0; i < 10; i++)
            P[dir][i] = (const float*)d_in[1 + dir * 10 + i];

    float* ws = (float*)d_ws;
    unsigned short* xzb0 = (unsigned short*)(ws);             // 2,048,000 fl
    unsigned short* xzb1 = (unsigned short*)(ws + 2048000);
    unsigned short* ucb0 = (unsigned short*)(ws + 4096000);   // 1,024,000 fl
    unsigned short* ucb1 = (unsigned short*)(ws + 5120000);
    float* dtT0 = ws + 6144000;                                // 2,048,000 fl
    float* dtT1 = ws + 8192000;
    unsigned short* xcb0 = (unsigned short*)(ws + 10240000);  // 1,024,000 fl
    unsigned short* xcb1 = (unsigned short*)(ws + 11264000);
    unsigned short* xnb0 = (unsigned short*)(ws + 12288000);  //   512,000 fl
    unsigned short* xnb1 = (unsigned short*)(ws + 12800000);
    unsigned short* wib0 = (unsigned short*)(ws + 13312000);  //   524,288 fl
    unsigned short* wib1 = (unsigned short*)(ws + 13836288);
    unsigned short* xpb0 = (unsigned short*)(ws + 14360576);  //    81,920 fl
    unsigned short* xpb1 = (unsigned short*)(ws + 14442496);
    unsigned short* dwb0 = (unsigned short*)(ws + 14524416);  //    16,384 fl
    unsigned short* dwb1 = (unsigned short*)(ws + 14540800);  // ends 14,557,184 fl (58 MB)
    // aliases (lifetimes disjoint, stream-ordered):
    unsigned short* ygb0 = xcb0;      // xcb dead after gemm_xp
    unsigned short* ygb1 = xcb1;
    unsigned short* wob0 = wib0;      // wib dead after gemm1
    unsigned short* wob1 = wib1;
    float* partial = dtT0;            // dtT dead after gate (2,048,000 fl)
    float* bct = (float*)d_out;       // BCT scratch lives in d_out until reduce
    float* out = (float*)d_out;

    rmsnorm_k<<<MROWS, 256, 0, stream>>>(x, P[0][0], P[1][0], xnb0, xnb1);

    cvt2_k<<<dim3(1024, 2), 256, 0, stream>>>(P[0][1], P[1][1], wib0, wib1, 262144);

    gemm1_mfma<<<dim3(16, 16, 2), 256, 0, stream>>>(
        xnb0, xnb1, wib0, wib1, xzb0, xzb1);

    cvt_xpdw_k<<<dim3(160, 4), 256, 0, stream>>>(
        P[0][4], P[1][4], P[0][5], P[1][5], xpb0, xpb1, dwb0, dwb1);

    conv_silu_k<<<dim3(16, 16, 4), 256, 0, stream>>>(
        xzb0, xzb1, P[0][2], P[1][2], P[0][3], P[1][3],
        ucb0, ucb1, xcb0, xcb1);

    gemm_xp_mfma<<<dim3(16, 4), 256, 0, stream>>>(
        xcb0, xcb1, xpb0, xpb1, dwb0, dwb1, P[0][6], P[1][6],
        dtT0, dtT1, bct);

    scan_k<<<dim3(256, 4), 256, 0, stream>>>(
        dtT0, dtT1, ucb0, ucb1, bct,
        P[0][7], P[1][7], P[0][8], P[1][8]);

    gate_k<<<dim3(16, 16, 4), 256, 0, stream>>>(
        dtT0, dtT1, xzb0, xzb1, ygb0, ygb1);

    cvt2_k<<<dim3(512, 2), 256, 0, stream>>>(P[0][9], P[1][9], wob0, wob1, 131072);

    gemm_out_mfma<<<dim3(4, 16, 2), 256, 0, stream>>>(
        ygb0, ygb1, wob0, wob1, partial);

    reduce_out_k<<<1000, 256, 0, stream>>>(x, partial, out);
}

// Round 11
// 296.317 us; speedup vs baseline: 1.2356x; 1.2356x over previous
//
#include <hip/hip_runtime.h>
#include <hip/hip_bf16.h>
#include <math.h>

#define DM   512
#define DI   1024
#define NS   64
#define RDT  32
#define BB   2
#define LL   1000
#define MROWS (BB*LL)   // 2000

typedef __attribute__((ext_vector_type(8))) short bf16x8;
typedef __attribute__((ext_vector_type(4))) float f32x4;

// f32 -> bf16 RNE (finite inputs)
__device__ __forceinline__ unsigned short f2bf(float f) {
    unsigned u = __builtin_bit_cast(unsigned, f);
    u = (u + 0x7FFF + ((u >> 16) & 1)) >> 16;
    return (unsigned short)u;
}
__device__ __forceinline__ float bf2f(unsigned short h) {
    unsigned u = (unsigned)h << 16;
    return __builtin_bit_cast(float, u);
}
__device__ __forceinline__ float bcast_lane(float v, int lane) {
    return __builtin_bit_cast(float,
        __builtin_amdgcn_readlane(__builtin_bit_cast(int, v), lane));
}

// ------------------- rmsnorm -> per-dir bf16 (norm_w folded) ----------------
__global__ __launch_bounds__(256)
void rmsnorm_k(const float* __restrict__ x,
               const float* __restrict__ nw0, const float* __restrict__ nw1,
               unsigned short* __restrict__ xnb0, unsigned short* __restrict__ xnb1) {
    int row = blockIdx.x;
    int tid = threadIdx.x;
    const float* xr = x + (size_t)row * DM;
    float2 v = *(const float2*)(xr + tid * 2);
    float ss = v.x * v.x + v.y * v.y;
    #pragma unroll
    for (int off = 32; off; off >>= 1) ss += __shfl_xor(ss, off, 64);
    __shared__ float red[4];
    if ((tid & 63) == 0) red[tid >> 6] = ss;
    __syncthreads();
    float tot = red[0] + red[1] + red[2] + red[3];
    float scale = rsqrtf(tot / (float)DM + 1e-5f);
    float2 w0 = *(const float2*)(nw0 + tid * 2);
    float2 w1 = *(const float2*)(nw1 + tid * 2);
    short2 o0, o1;
    o0.x = (short)f2bf(v.x * scale * w0.x);
    o0.y = (short)f2bf(v.y * scale * w0.y);
    o1.x = (short)f2bf(v.x * scale * w1.x);
    o1.y = (short)f2bf(v.y * scale * w1.y);
    *(short2*)(xnb0 + (size_t)row * DM + tid * 2) = o0;
    *(short2*)(xnb1 + (size_t)row * DM + tid * 2) = o1;
}

// ------------------------------------ f32 -> bf16 convert, 2 arrays batched --
__global__ __launch_bounds__(256)
void cvt2_k(const float* __restrict__ in0, const float* __restrict__ in1,
            unsigned short* __restrict__ out0, unsigned short* __restrict__ out1,
            int n4) {
    int idx = blockIdx.x * 256 + threadIdx.x;
    if (idx >= n4) return;
    const float* in = blockIdx.y ? in1 : in0;
    unsigned short* out = blockIdx.y ? out1 : out0;
    float4 v = *(const float4*)(in + (size_t)idx * 4);
    short4 o;
    o.x = (short)f2bf(v.x); o.y = (short)f2bf(v.y);
    o.z = (short)f2bf(v.z); o.w = (short)f2bf(v.w);
    *(short4*)(out + (size_t)idx * 4) = o;
}

// ------ GEMM1 (in_proj) bf16 MFMA: xzb[dir] = bf16( xn_dir @ W^T ) ----------
__global__ __launch_bounds__(256, 2)
void gemm1_mfma(const unsigned short* __restrict__ xnb0,
                const unsigned short* __restrict__ xnb1,
                const unsigned short* __restrict__ wib0,
                const unsigned short* __restrict__ wib1,
                unsigned short* __restrict__ xzb0, unsigned short* __restrict__ xzb1)
{
    __shared__ __align__(16) unsigned short As[128 * 40];
    __shared__ __align__(16) unsigned short Bs[128 * 40];
    int dir = blockIdx.z;
    const unsigned short* A = dir ? xnb1 : xnb0;
    const unsigned short* W = dir ? wib1 : wib0;
    unsigned short* C = dir ? xzb1 : xzb0;
    int n0 = blockIdx.x * 128, m0 = blockIdx.y * 128;
    int tid = threadIdx.x;
    int wv = tid >> 6, lane = tid & 63;
    int wr = wv >> 1, wc = wv & 1;
    int fl = lane & 15, kg = lane >> 4;

    f32x4 acc[4][4];
    #pragma unroll
    for (int i = 0; i < 4; i++)
        #pragma unroll
        for (int j = 0; j < 4; j++) acc[i][j] = (f32x4){0.f, 0.f, 0.f, 0.f};

    int sr = tid >> 2, cg = tid & 3;
    for (int k0 = 0; k0 < 512; k0 += 32) {
        #pragma unroll
        for (int i = 0; i < 2; i++) {
            int row = sr + i * 64;
            int m = m0 + row;
            float4 av = make_float4(0.f, 0.f, 0.f, 0.f);
            if (m < MROWS) {
                int rs = m;
                if (dir) { int b = m / LL, t = m % LL; rs = b * LL + (LL - 1 - t); }
                av = *(const float4*)(A + (size_t)rs * 512 + k0 + cg * 8);
            }
            *(float4*)(&As[row * 40 + cg * 8]) = av;
            float4 wv4 = *(const float4*)(W + (size_t)(n0 + row) * 512 + k0 + cg * 8);
            *(float4*)(&Bs[row * 40 + cg * 8]) = wv4;
        }
        __syncthreads();
        bf16x8 af[4], bf[4];
        #pragma unroll
        for (int fr = 0; fr < 4; fr++)
            af[fr] = *(const bf16x8*)(&As[(wr * 64 + fr * 16 + fl) * 40 + kg * 8]);
        #pragma unroll
        for (int fc = 0; fc < 4; fc++)
            bf[fc] = *(const bf16x8*)(&Bs[(wc * 64 + fc * 16 + fl) * 40 + kg * 8]);
        #pragma unroll
        for (int fr = 0; fr < 4; fr++)
            #pragma unroll
            for (int fc = 0; fc < 4; fc++)
                acc[fr][fc] = __builtin_amdgcn_mfma_f32_16x16x32_bf16(
                    af[fr], bf[fc], acc[fr][fc], 0, 0, 0);
        __syncthreads();
    }
    #pragma unroll
    for (int fr = 0; fr < 4; fr++)
        #pragma unroll
        for (int fc = 0; fc < 4; fc++)
            #pragma unroll
            for (int j = 0; j < 4; j++) {
                int m = m0 + wr * 64 + fr * 16 + kg * 4 + j;
                if (m < MROWS) {
                    int n = n0 + wc * 64 + fc * 16 + fl;
                    C[(size_t)m * 2048 + n] = f2bf(acc[fr][fc][j]);
                }
            }
}

// -------- out_proj bf16 MFMA, 128x128 tile, full K, per-dir -> partials -----
__global__ __launch_bounds__(256, 2)
void gemm_out_mfma(const unsigned short* __restrict__ ygb0,
                   const unsigned short* __restrict__ ygb1,
                   const unsigned short* __restrict__ wob0,
                   const unsigned short* __restrict__ wob1,
                   float* __restrict__ partial)
{
    __shared__ __align__(16) unsigned short As[128 * 40];
    __shared__ __align__(16) unsigned short Bs[128 * 40];
    int dir = blockIdx.z;
    const unsigned short* A = dir ? ygb1 : ygb0;   // (2000,1024)
    const unsigned short* W = dir ? wob1 : wob0;   // (512,1024)
    float* P = partial + (size_t)dir * MROWS * 512;
    int n0 = blockIdx.x * 128, m0 = blockIdx.y * 128;
    int tid = threadIdx.x;
    int wv = tid >> 6, lane = tid & 63;
    int wr = wv >> 1, wc = wv & 1;
    int fl = lane & 15, kg = lane >> 4;

    f32x4 acc[4][4];
    #pragma unroll
    for (int i = 0; i < 4; i++)
        #pragma unroll
        for (int j = 0; j < 4; j++) acc[i][j] = (f32x4){0.f, 0.f, 0.f, 0.f};

    int sr = tid >> 2, cg = tid & 3;
    for (int k0 = 0; k0 < 1024; k0 += 32) {
        #pragma unroll
        for (int i = 0; i < 2; i++) {
            int row = sr + i * 64;
            int m = m0 + row;
            float4 av = make_float4(0.f, 0.f, 0.f, 0.f);
            if (m < MROWS)
                av = *(const float4*)(A + (size_t)m * 1024 + k0 + cg * 8);
            *(float4*)(&As[row * 40 + cg * 8]) = av;
            float4 wv4 = *(const float4*)(W + (size_t)(n0 + sr + i * 64) * 1024 + k0 + cg * 8);
            *(float4*)(&Bs[row * 40 + cg * 8]) = wv4;
        }
        __syncthreads();
        bf16x8 af[4], bf[4];
        #pragma unroll
        for (int fr = 0; fr < 4; fr++)
            af[fr] = *(const bf16x8*)(&As[(wr * 64 + fr * 16 + fl) * 40 + kg * 8]);
        #pragma unroll
        for (int fc = 0; fc < 4; fc++)
            bf[fc] = *(const bf16x8*)(&Bs[(wc * 64 + fc * 16 + fl) * 40 + kg * 8]);
        #pragma unroll
        for (int fr = 0; fr < 4; fr++)
            #pragma unroll
            for (int fc = 0; fc < 4; fc++)
                acc[fr][fc] = __builtin_amdgcn_mfma_f32_16x16x32_bf16(
                    af[fr], bf[fc], acc[fr][fc], 0, 0, 0);
        __syncthreads();
    }
    #pragma unroll
    for (int fr = 0; fr < 4; fr++)
        #pragma unroll
        for (int fc = 0; fc < 4; fc++)
            #pragma unroll
            for (int j = 0; j < 4; j++) {
                int m = m0 + wr * 64 + fr * 16 + kg * 4 + j;
                if (m < MROWS) {
                    int n = n0 + wc * 64 + fc * 16 + fl;
                    P[(size_t)m * 512 + n] = acc[fr][fc][j];
                }
            }
}

// out[m] = 2x[m] + pf[m] + pb[flip(m)]
__global__ __launch_bounds__(256)
void reduce_out_k(const float* __restrict__ x, const float* __restrict__ partial,
                  float* __restrict__ out)
{
    int idx = blockIdx.x * 256 + threadIdx.x;
    if (idx >= MROWS * 128) return;
    int m = idx >> 7, q = idx & 127;
    int b = m / LL, t = m % LL;
    int fm = b * LL + (LL - 1 - t);
    const float* p0 = partial;
    const float* p1 = partial + (size_t)MROWS * 512;
    float4 xv = *(const float4*)(x  + (size_t)m  * 512 + q * 4);
    float4 a  = *(const float4*)(p0 + (size_t)m  * 512 + q * 4);
    float4 c  = *(const float4*)(p1 + (size_t)fm * 512 + q * 4);
    float4 o;
    o.x = 2.f * xv.x + a.x + c.x;
    o.y = 2.f * xv.y + a.y + c.y;
    o.z = 2.f * xv.z + a.z + c.z;
    o.w = 2.f * xv.w + a.w + c.w;
    *(float4*)(out + (size_t)m * 512 + q * 4) = o;
}

// ---- causal dwconv + silu -> xcT f32 [b][d][t]  AND  xcb bf16 [t][d] -------
__global__ __launch_bounds__(256)
void conv_silu_k(const unsigned short* __restrict__ xzb0,
                 const unsigned short* __restrict__ xzb1,
                 const float* __restrict__ cw0, const float* __restrict__ cw1,
                 const float* __restrict__ cb0, const float* __restrict__ cb1,
                 float* __restrict__ xcT0, float* __restrict__ xcT1,
                 unsigned short* __restrict__ xcb0, unsigned short* __restrict__ xcb1)
{
    __shared__ float Ls[64 * 65];
    int dirb = blockIdx.z;
    int dir = dirb >> 1, b = dirb & 1;
    int d0 = blockIdx.x * 64, t0 = blockIdx.y * 64;
    int tid = threadIdx.x;
    int dl = tid & 63, tg = tid >> 6;

    const unsigned short* in = (dir ? xzb1 : xzb0) + (size_t)b * LL * 2048;
    const float* cw = dir ? cw1 : cw0;
    const float* cb = dir ? cb1 : cb0;
    float*      xcT = dir ? xcT1 : xcT0;
    unsigned short* xcb = dir ? xcb1 : xcb0;

    float4 w4 = ((const float4*)cw)[d0 + dl];
    float bias = cb[d0 + dl];

    int ts = t0 + tg * 16;
    float x3 = 0.f, x2 = 0.f, x1 = 0.f;
    if (ts - 3 >= 0 && ts - 3 < LL) x3 = bf2f(in[(size_t)(ts - 3) * 2048 + d0 + dl]);
    if (ts - 2 >= 0 && ts - 2 < LL) x2 = bf2f(in[(size_t)(ts - 2) * 2048 + d0 + dl]);
    if (ts - 1 >= 0 && ts - 1 < LL) x1 = bf2f(in[(size_t)(ts - 1) * 2048 + d0 + dl]);

    #pragma unroll
    for (int i = 0; i < 16; i++) {
        int t = ts + i;
        float x0v = (t < LL) ? bf2f(in[(size_t)t * 2048 + d0 + dl]) : 0.f;
        float a = bias + x3 * w4.x + x2 * w4.y + x1 * w4.z + x0v * w4.w;
        float s = a / (1.f + __expf(-a));
        Ls[dl * 65 + tg * 16 + i] = s;
        if (t < LL)
            xcb[((size_t)(b * LL + t)) * 1024 + d0 + dl] = f2bf(s);
        x3 = x2; x2 = x1; x1 = x0v;
    }
    __syncthreads();
    int tl = tid & 63, dg = tid >> 6;
    #pragma unroll
    for (int i = 0; i < 16; i++) {
        int dd = dg * 16 + i;
        int t = t0 + tl;
        if (t < LL)
            xcT[((size_t)(b * 1024) + d0 + dd) * LL + t] = Ls[dd * 65 + tl];
    }
}

// --------------- x_proj bf16 MFMA: per (dirb) 1000x160 = xcb @ xp^T ---------
// outputs: xd [t][32] f32 (dt_raw cols 0..31), bct[dirb][n-32][t] (cols 32..159)
__global__ __launch_bounds__(256, 2)
void gemm_xp_mfma(const unsigned short* __restrict__ xcb0,
                  const unsigned short* __restrict__ xcb1,
                  const unsigned short* __restrict__ xpb0,
                  const unsigned short* __restrict__ xpb1,
                  float* __restrict__ xd0, float* __restrict__ xd1,
                  float* __restrict__ bct)
{
    __shared__ __align__(16) unsigned short As[64 * 40];
    __shared__ __align__(16) unsigned short Ws[160 * 40];
    int dirb = blockIdx.y;
    int dir = dirb >> 1, b = dirb & 1;
    const unsigned short* A = (dir ? xcb1 : xcb0) + (size_t)b * LL * 1024;
    const unsigned short* W = dir ? xpb1 : xpb0;   // (160,1024)
    float* xd = (dir ? xd1 : xd0) + (size_t)b * LL * 32;
    float* bc = bct + (size_t)dirb * 128 * LL;
    int m0 = blockIdx.x * 64;
    int tid = threadIdx.x;
    int wv = tid >> 6, lane = tid & 63;
    int fl = lane & 15, kg = lane >> 4;

    f32x4 acc[10];
    #pragma unroll
    for (int f = 0; f < 10; f++) acc[f] = (f32x4){0.f, 0.f, 0.f, 0.f};

    int sr = tid >> 2, cg = tid & 3;
    for (int k0 = 0; k0 < 1024; k0 += 32) {
        {   // A tile 64x32
            int t = m0 + sr;
            float4 av = make_float4(0.f, 0.f, 0.f, 0.f);
            if (t < LL)
                av = *(const float4*)(A + (size_t)t * 1024 + k0 + cg * 8);
            *(float4*)(&As[sr * 40 + cg * 8]) = av;
        }
        #pragma unroll
        for (int it = 0; it < 3; it++) {   // W tile 160x32
            int row = sr + it * 64;
            if (row < 160) {
                float4 wv4 = *(const float4*)(W + (size_t)row * 1024 + k0 + cg * 8);
                *(float4*)(&Ws[row * 40 + cg * 8]) = wv4;
            }
        }
        __syncthreads();
        bf16x8 af = *(const bf16x8*)(&As[(wv * 16 + fl) * 40 + kg * 8]);
        #pragma unroll
        for (int f = 0; f < 10; f++) {
            bf16x8 bf = *(const bf16x8*)(&Ws[(f * 16 + fl) * 40 + kg * 8]);
            acc[f] = __builtin_amdgcn_mfma_f32_16x16x32_bf16(af, bf, acc[f], 0, 0, 0);
        }
        __syncthreads();
    }

    // epilogue: f=0,1 -> xd[t][32]; f=2..9 -> bct[n-32][t]
    #pragma unroll
    for (int f = 0; f < 10; f++) {
        int n = f * 16 + fl;
        #pragma unroll
        for (int j = 0; j < 4; j++) {
            int t = m0 + wv * 16 + kg * 4 + j;
            if (t >= LL) continue;
            if (f < 2) xd[(size_t)t * 32 + n] = acc[f][j];
            else       bc[(size_t)(n - 32) * LL + t] = acc[f][j];
        }
    }
}

// ---- dt GEMM (K=32) + softplus, output TRANSPOSED dtT [b][d][t] ------------
__global__ __launch_bounds__(256)
void gemm_dt_k(const float* __restrict__ xd0, const float* __restrict__ xd1,
               const float* __restrict__ w0, const float* __restrict__ w1,
               const float* __restrict__ bb0, const float* __restrict__ bb1,
               float* __restrict__ dtT0, float* __restrict__ dtT1)
{
    __shared__ float As[64 * 33];
    __shared__ float Ws[32 * 68];
    __shared__ float T[64 * 67];
    int dirb = blockIdx.z;
    int dir = dirb >> 1, b = dirb & 1;
    const float* xd = (dir ? xd1 : xd0) + (size_t)b * LL * 32;
    const float* W  = dir ? w1 : w0;
    const float* bi = dir ? bb1 : bb0;
    float*      dtT = (dir ? dtT1 : dtT0) + (size_t)b * 1024 * LL;
    int n0 = blockIdx.x * 64, t0 = blockIdx.y * 64;
    int tid = threadIdx.x;
    int tx = tid & 15, ty = tid >> 4;

    #pragma unroll
    for (int i = 0; i < 2; i++) {
        int j = tid + 256 * i;
        int row = j >> 3, q = j & 7;
        float4 v = make_float4(0.f, 0.f, 0.f, 0.f);
        if (t0 + row < LL)
            v = *(const float4*)(xd + (size_t)(t0 + row) * 32 + (q & 7) * 4);
        As[row * 33 + q * 4 + 0] = v.x;
        As[row * 33 + q * 4 + 1] = v.y;
        As[row * 33 + q * 4 + 2] = v.z;
        As[row * 33 + q * 4 + 3] = v.w;
        float4 wv = *(const float4*)(W + (size_t)(n0 + row) * 32 + q * 4);
        Ws[(q * 4 + 0) * 68 + row] = wv.x;
        Ws[(q * 4 + 1) * 68 + row] = wv.y;
        Ws[(q * 4 + 2) * 68 + row] = wv.z;
        Ws[(q * 4 + 3) * 68 + row] = wv.w;
    }
    __syncthreads();

    float acc[4][4] = {};
    #pragma unroll 8
    for (int k = 0; k < 32; k++) {
        float4 w = *(const float4*)(Ws + k * 68 + tx * 4);
        float wvv[4] = {w.x, w.y, w.z, w.w};
        float av[4];
        #pragma unroll
        for (int i = 0; i < 4; i++) av[i] = As[(ty * 4 + i) * 33 + k];
        #pragma unroll
        for (int i = 0; i < 4; i++)
            #pragma unroll
            for (int j = 0; j < 4; j++)
                acc[i][j] = fmaf(av[i], wvv[j], acc[i][j]);
    }
    __syncthreads();

    #pragma unroll
    for (int i = 0; i < 4; i++) {
        #pragma unroll
        for (int j = 0; j < 4; j++) {
            int n = tx * 4 + j;
            float v = acc[i][j] + bi[n0 + n];
            v = (v > 20.f) ? v : log1pf(__expf(v));
            T[n * 67 + ty * 4 + i] = v;
        }
    }
    __syncthreads();

    int tl = tid & 63, ng = tid >> 6;
    #pragma unroll
    for (int i = 0; i < 16; i++) {
        int nl = ng * 16 + i;
        int t = t0 + tl;
        if (t < LL)
            dtT[(size_t)(n0 + nl) * LL + t] = T[nl * 67 + tl];
    }
}

// ------------------------------------------------------------ selective scan
// T14 async-stage (round-8 proven structure, f32 u)
__global__ __launch_bounds__(256)
void scan_k(float* __restrict__ dtT0, float* __restrict__ dtT1,
            const float* __restrict__ ucT0, const float* __restrict__ ucT1,
            const float* __restrict__ bct,
            const float* __restrict__ Al0, const float* __restrict__ Al1,
            const float* __restrict__ Dc0, const float* __restrict__ Dc1)
{
    __shared__ float Bs[64 * 34];
    __shared__ float Cs[64 * 34];
    __shared__ float Pt[4][16 * 66];
    int dirb = blockIdx.y;
    int dir = dirb >> 1, b = dirb & 1;
    int wid = threadIdx.x >> 6, lane = threadIdx.x & 63;
    int d = blockIdx.x * 4 + wid;
    float* Pw = Pt[wid];

    float*       dtT = (dir ? dtT1 : dtT0);
    const float* ucT = (dir ? ucT1 : ucT0);
    const float* Al  = dir ? Al1 : Al0;
    const float* Dc  = dir ? Dc1 : Dc0;

    float a  = -__expf(Al[d * 64 + lane]) * 1.44269504f;
    float Dp = Dc[d];
    float h  = 0.f;
    size_t chan = ((size_t)(b * 1024 + d)) * LL;
    const float* Bg = bct + (size_t)dirb * 128 * LL;

    int srow = threadIdx.x >> 2;
    int scol = (threadIdx.x & 3) * 8;
    int tl16 = lane & 15, qq = lane >> 4;
    const float* Prow = Pw + tl16 * 66 + qq * 16;

    float4 rb0, rb1, rc0, rc1;
    float dta = 0.f, ua = 0.f;
    {
        const float* Bp = Bg + (size_t)srow * LL + scol;
        const float* Cp = Bg + (size_t)(srow + 64) * LL + scol;
        rb0 = *(const float4*)(Bp);     rb1 = *(const float4*)(Bp + 4);
        rc0 = *(const float4*)(Cp);     rc1 = *(const float4*)(Cp + 4);
        if (lane < 32) {
            dta = dtT[chan + lane];
            ua  = ucT[chan + lane];
        }
    }

    for (int t0 = 0; t0 < LL; t0 += 32) {
        int rem = min(32, LL - t0);
        __syncthreads();
        *(float4*)(&Bs[srow * 34 + scol])     = rb0;
        *(float4*)(&Bs[srow * 34 + scol + 4]) = rb1;
        *(float4*)(&Cs[srow * 34 + scol])     = rc0;
        *(float4*)(&Cs[srow * 34 + scol + 4]) = rc1;
        float dcur = dta, ucur = ua;
        float wsc  = dcur * ucur;
        __syncthreads();

        if (t0 + 32 < LL) {
            const float* Bp = Bg + (size_t)srow * LL + (t0 + 32) + scol;
            const float* Cp = Bg + (size_t)(srow + 64) * LL + (t0 + 32) + scol;
            rb0 = *(const float4*)(Bp);     rb1 = *(const float4*)(Bp + 4);
            rc0 = *(const float4*)(Cp);     rc1 = *(const float4*)(Cp + 4);
            if (lane < min(32, LL - t0 - 32)) {
                dta = dtT[chan + t0 + 32 + lane];
                ua  = ucT[chan + t0 + 32 + lane];
            }
        }

        for (int sec = 0; sec < 2; sec++) {
            int sbase = sec * 16;
            int steps = rem - sbase;
            if (steps <= 0) break;
            if (steps > 16) steps = 16;
            if (steps < 16) {
                for (int i = steps; i < 16; i++) Pw[i * 66 + lane] = 0.f;
            }
            int ngr = (steps + 7) >> 3;
            for (int g = 0; g < ngr; g++) {
                int tb = sbase + g * 8;
                float4 B0 = *(const float4*)(&Bs[lane * 34 + tb]);
                float4 B1 = *(const float4*)(&Bs[lane * 34 + tb + 4]);
                float4 C0 = *(const float4*)(&Cs[lane * 34 + tb]);
                float4 C1 = *(const float4*)(&Cs[lane * 34 + tb + 4]);
                #pragma unroll
                for (int i = 0; i < 8; i++) {
                    float dtv = bcast_lane(dcur, tb + i);
                    float w   = bcast_lane(wsc,  tb + i);
                    float dA  = exp2f(dtv * a);
                    float Bn  = (i < 4) ? B0[i] : B1[i - 4];
                    float Cn  = (i < 4) ? C0[i] : C1[i - 4];
                    h = fmaf(dA, h, w * Bn);
                    Pw[(g * 8 + i) * 66 + lane] = h * Cn;
                }
            }
            float s = 0.f;
            #pragma unroll
            for (int j = 0; j < 8; j++) {
                float2 v = *(const float2*)(Prow + j * 2);
                s += v.x + v.y;
            }
#if __has_builtin(__builtin_amdgcn_permlane32_swap)
            {
                unsigned aa = __builtin_bit_cast(unsigned, s);
                auto r = __builtin_amdgcn_permlane32_swap(aa, aa, false, false);
                s = __builtin_bit_cast(float, (unsigned)r[0]) +
                    __builtin_bit_cast(float, (unsigned)r[1]);
            }
#else
            s += __shfl_xor(s, 32, 64);
#endif
#if __has_builtin(__builtin_amdgcn_permlane16_swap)
            {
                unsigned aa = __builtin_bit_cast(unsigned, s);
                auto r = __builtin_amdgcn_permlane16_swap(aa, aa, false, false);
                s = __builtin_bit_cast(float, (unsigned)r[0]) +
                    __builtin_bit_cast(float, (unsigned)r[1]);
            }
#else
            s += __shfl_xor(s, 16, 64);
#endif
            float uf = __shfl(ucur, sbase + tl16, 64);
            s = fmaf(uf, Dp, s);
            if (lane < steps)
                dtT[chan + t0 + sbase + lane] = s;
        }
    }
}

// ------- gate: ygb[t][d] = bf16( yT[d][t] * silu(z[t][1024+d]) ) ------------
__global__ __launch_bounds__(256)
void gate_k(const float* __restrict__ yT0, const float* __restrict__ yT1,
            const unsigned short* __restrict__ xzb0,
            const unsigned short* __restrict__ xzb1,
            unsigned short* __restrict__ yg0, unsigned short* __restrict__ yg1)
{
    __shared__ float Ls[64 * 65];
    int dirb = blockIdx.z;
    int dir = dirb >> 1, b = dirb & 1;
    int d0 = blockIdx.x * 64, t0 = blockIdx.y * 64;
    int tid = threadIdx.x;
    const float* yT = (dir ? yT1 : yT0) + (size_t)b * 1024 * LL;
    const unsigned short* xz = (dir ? xzb1 : xzb0) + (size_t)b * LL * 2048;
    unsigned short* yg = dir ? yg1 : yg0;

    int tl = tid & 63, dg = tid >> 6;
    #pragma unroll
    for (int i = 0; i < 16; i++) {
        int dd = dg * 16 + i;
        int t = t0 + tl;
        float v = (t < LL) ? yT[(size_t)(d0 + dd) * LL + t] : 0.f;
        Ls[dd * 65 + tl] = v;
    }
    __syncthreads();
    int dcol = tid & 63, tg = tid >> 6;
    #pragma unroll
    for (int i = 0; i < 16; i++) {
        int t = t0 + tg * 16 + i;
        if (t >= LL) continue;
        float z = bf2f(xz[(size_t)t * 2048 + 1024 + d0 + dcol]);
        float y = Ls[dcol * 65 + tg * 16 + i];
        float s = z / (1.f + __expf(-z));
        yg[((size_t)(b * LL + t)) * 1024 + d0 + dcol] = f2bf(y * s);
    }
}

// -------------------------------------------------------------------- launch
extern "C" void kernel_launch(void* const* d_in, const int* in_sizes, int n_in,
                              void* d_out, int out_size, void* d_ws, size_t ws_size,
                              hipStream_t stream) {
    const float* x = (const float*)d_in[0];
    const float* P[2][10];
    for (int dir = 0; dir < 2; dir++)
        for (int i = 0; i < 10; i++)
            P[dir][i] = (const float*)d_in[1 + dir * 10 + i];

    float* ws = (float*)d_ws;
    unsigned short* xzb0 = (unsigned short*)(ws);             // in xz0 region
    unsigned short* xzb1 = (unsigned short*)(ws + 4096000);   // in xz1 region
    float* xcT0  = ws + 8192000;          // 2,048,000
    float* xcT1  = ws + 10240000;         // 2,048,000
    float* dtT0  = ws + 12288000;         // 2,048,000
    float* dtT1  = ws + 14336000;         // 2,048,000
    float* xdbl0 = ws + 16384000;         //    64,000
    float* xdbl1 = ws + 16448000;         //    64,000
    unsigned short* xnb0 = (unsigned short*)(ws + 17024000);  // 256,000 fl
    unsigned short* xnb1 = (unsigned short*)(ws + 17280000);  // 256,000 fl
    // aliases (lifetimes disjoint, stream-ordered):
    unsigned short* wib0 = (unsigned short*)(ws + 14336000);  // dtT1 region, dead before gemm_dt
    unsigned short* wib1 = (unsigned short*)(ws + 14860288);
    unsigned short* xcb0 = (unsigned short*)(ws + 12288000);  // dtT0 region, dead before gemm_dt
    unsigned short* xcb1 = (unsigned short*)(ws + 13312000);
    unsigned short* xpb0 = (unsigned short*)(ws + 17024000);  // xnb region, after gemm1
    unsigned short* xpb1 = (unsigned short*)(ws + 17280000);
    unsigned short* ygb0 = (unsigned short*)xcT0;   // xcT dead after scan
    unsigned short* ygb1 = (unsigned short*)xcT1;
    unsigned short* wob0 = (unsigned short*)dtT0;   // dtT dead after gate
    unsigned short* wob1 = (unsigned short*)(dtT0 + 262144);
    float* partial = ws;                            // xz regions dead after gate
    float* bct = (float*)d_out;                     // BCT scratch lives in d_out
    float* out = (float*)d_out;

    rmsnorm_k<<<MROWS, 256, 0, stream>>>(x, P[0][0], P[1][0], xnb0, xnb1);

    cvt2_k<<<dim3(1024, 2), 256, 0, stream>>>(P[0][1], P[1][1], wib0, wib1, 262144);

    gemm1_mfma<<<dim3(16, 16, 2), 256, 0, stream>>>(
        xnb0, xnb1, wib0, wib1, xzb0, xzb1);

    // x_proj weights -> bf16 (reuses dead xnb slots)
    cvt2_k<<<dim3(160, 2), 256, 0, stream>>>(P[0][4], P[1][4], xpb0, xpb1, 40960);

    conv_silu_k<<<dim3(16, 16, 4), 256, 0, stream>>>(
        xzb0, xzb1, P[0][2], P[1][2], P[0][3], P[1][3], xcT0, xcT1, xcb0, xcb1);

    gemm_xp_mfma<<<dim3(16, 4), 256, 0, stream>>>(
        xcb0, xcb1, xpb0, xpb1, xdbl0, xdbl1, bct);

    gemm_dt_k<<<dim3(16, 16, 4), 256, 0, stream>>>(
        xdbl0, xdbl1, P[0][5], P[1][5], P[0][6], P[1][6], dtT0, dtT1);

    scan_k<<<dim3(256, 4), 256, 0, stream>>>(
        dtT0, dtT1, xcT0, xcT1, bct,
        P[0][7], P[1][7], P[0][8], P[1][8]);

    gate_k<<<dim3(16, 16, 4), 256, 0, stream>>>(
        dtT0, dtT1, xzb0, xzb1, ygb0, ygb1);

    cvt2_k<<<dim3(512, 2), 256, 0, stream>>>(P[0][9], P[1][9], wob0, wob1, 131072);

    gemm_out_mfma<<<dim3(4, 16, 2), 256, 0, stream>>>(
        ygb0, ygb1, wob0, wob1, partial);

    reduce_out_k<<<1000, 256, 0, stream>>>(x, partial, out);
}